// Round 1
// baseline (1150.902 us; speedup 1.0000x reference)
//
#include <hip/hip_runtime.h>
#include <math.h>

#define NN   10000
#define IND  512
#define HID  256
#define NE   400000

// ---------------- generic f32 tiled GEMM: C[M,N] = A[M,K] @ B[K,N] (row-major)
#define BM 64
#define BN 64
#define BK 16

__global__ __launch_bounds__(256) void gemm_f32(
    const float* __restrict__ A, const float* __restrict__ B,
    float* __restrict__ C, int M, int K, int N)
{
    __shared__ float As[BK][BM];   // A tile transposed: As[k][m]
    __shared__ float Bs[BK][BN];

    const int tid  = threadIdx.x;
    const int tx   = tid & 15;     // col group (4 cols each)
    const int ty   = tid >> 4;     // row group (4 rows each)
    const int row0 = blockIdx.y * BM;
    const int col0 = blockIdx.x * BN;

    float acc[4][4] = {{0.f}};

    // A-load: thread loads float4 along K of one row
    const int a_row = tid >> 2;          // 0..63
    const int a_k4  = (tid & 3) << 2;    // 0,4,8,12
    // B-load: thread loads float4 along N of one k-row
    const int b_k   = tid >> 4;          // 0..15
    const int b_c4  = (tid & 15) << 2;   // 0..60

    for (int k0 = 0; k0 < K; k0 += BK) {
        float4 av = make_float4(0.f, 0.f, 0.f, 0.f);
        if (row0 + a_row < M)
            av = *reinterpret_cast<const float4*>(&A[(size_t)(row0 + a_row) * K + (k0 + a_k4)]);
        const float4 bv = *reinterpret_cast<const float4*>(&B[(size_t)(k0 + b_k) * N + (col0 + b_c4)]);
        __syncthreads();
        As[a_k4 + 0][a_row] = av.x;
        As[a_k4 + 1][a_row] = av.y;
        As[a_k4 + 2][a_row] = av.z;
        As[a_k4 + 3][a_row] = av.w;
        *reinterpret_cast<float4*>(&Bs[b_k][b_c4]) = bv;
        __syncthreads();

        #pragma unroll
        for (int kk = 0; kk < BK; ++kk) {
            const float4 a4 = *reinterpret_cast<const float4*>(&As[kk][ty << 2]);
            const float4 b4 = *reinterpret_cast<const float4*>(&Bs[kk][tx << 2]);
            const float ar[4] = {a4.x, a4.y, a4.z, a4.w};
            const float br[4] = {b4.x, b4.y, b4.z, b4.w};
            #pragma unroll
            for (int i = 0; i < 4; ++i)
                #pragma unroll
                for (int j = 0; j < 4; ++j)
                    acc[i][j] = fmaf(ar[i], br[j], acc[i][j]);
        }
    }

    #pragma unroll
    for (int i = 0; i < 4; ++i) {
        const int r = row0 + (ty << 2) + i;
        if (r < M) {
            const float4 o = make_float4(acc[i][0], acc[i][1], acc[i][2], acc[i][3]);
            *reinterpret_cast<float4*>(&C[(size_t)r * N + col0 + (tx << 2)]) = o;
        }
    }
}

// ---------------- c[j] = sum_m W2[j,m] * W3[m,0]   (j in [0,512), m in [0,256))
__global__ void k_uv(const float* __restrict__ W2, const float* __restrict__ W3,
                     float* __restrict__ c)
{
    const int j = blockIdx.x * blockDim.x + threadIdx.x;
    if (j >= 2 * HID) return;
    float s = 0.f;
    for (int m = 0; m < HID; ++m)
        s = fmaf(W2[(size_t)j * HID + m], W3[m], s);
    c[j] = s;
}

// ---------------- per-node: a[n]=relu(z[n])·u, b[n]=relu(z[n])·v, zs[n]=z[n]*w3b
__global__ __launch_bounds__(256) void k_node(
    const float* __restrict__ z, const float* __restrict__ c,
    const float* __restrict__ W3, float* __restrict__ zs,
    float* __restrict__ av, float* __restrict__ bv)
{
    const int wave = (int)((blockIdx.x * blockDim.x + threadIdx.x) >> 6);
    const int lane = threadIdx.x & 63;
    if (wave >= NN) return;

    const float4 z4 = *reinterpret_cast<const float4*>(&z[(size_t)wave * HID + (lane << 2)]);
    const float4 w4 = *reinterpret_cast<const float4*>(&W3[HID + (lane << 2)]);   // w3b
    const float4 u4 = *reinterpret_cast<const float4*>(&c[(lane << 2)]);
    const float4 v4 = *reinterpret_cast<const float4*>(&c[HID + (lane << 2)]);

    const float4 zs4 = make_float4(z4.x * w4.x, z4.y * w4.y, z4.z * w4.z, z4.w * w4.w);
    *reinterpret_cast<float4*>(&zs[(size_t)wave * HID + (lane << 2)]) = zs4;

    const float r0 = fmaxf(z4.x, 0.f), r1 = fmaxf(z4.y, 0.f);
    const float r2 = fmaxf(z4.z, 0.f), r3 = fmaxf(z4.w, 0.f);
    float pa = r0 * u4.x + r1 * u4.y + r2 * u4.z + r3 * u4.w;
    float pb = r0 * v4.x + r1 * v4.y + r2 * v4.z + r3 * v4.w;

    #pragma unroll
    for (int off = 32; off; off >>= 1) {
        pa += __shfl_down(pa, off);
        pb += __shfl_down(pb, off);
    }
    if (lane == 0) { av[wave] = pa; bv[wave] = pb; }
}

// ---------------- per-edge: out = sigmoid(a[i] + b[j] + dot(zs[i], z[j]))
__global__ __launch_bounds__(256) void k_edge(
    const int* __restrict__ e1, const int* __restrict__ e2,
    const float* __restrict__ z, const float* __restrict__ zs,
    const float* __restrict__ av, const float* __restrict__ bv,
    float* __restrict__ out)
{
    const long long gw = (((long long)blockIdx.x * blockDim.x) + threadIdx.x) >> 6; // edge id
    const int lane = threadIdx.x & 63;
    if (gw >= 2LL * NE) return;

    const int* ep = (gw < NE) ? &e1[2 * (int)gw] : &e2[2 * ((int)gw - NE)];
    const int i = ep[0];
    const int j = ep[1];

    const float4 zi = *reinterpret_cast<const float4*>(&zs[(size_t)i * HID + (lane << 2)]);
    const float4 zj = *reinterpret_cast<const float4*>(&z[(size_t)j * HID + (lane << 2)]);
    float p = zi.x * zj.x + zi.y * zj.y + zi.z * zj.z + zi.w * zj.w;

    #pragma unroll
    for (int off = 32; off; off >>= 1)
        p += __shfl_down(p, off);

    if (lane == 0) {
        const float logit = av[i] + bv[j] + p;
        out[gw] = 1.f / (1.f + expf(-logit));
    }
}

extern "C" void kernel_launch(void* const* d_in, const int* in_sizes, int n_in,
                              void* d_out, int out_size, void* d_ws, size_t ws_size,
                              hipStream_t stream)
{
    const float* X   = (const float*)d_in[0];
    const float* adj = (const float*)d_in[1];
    const int*   e1  = (const int*)d_in[2];
    const int*   e2  = (const int*)d_in[3];
    const float* W   = (const float*)d_in[4];
    const float* W2  = (const float*)d_in[5];
    const float* W3  = (const float*)d_in[6];
    float* out = (float*)d_out;

    float* ws = (float*)d_ws;
    float* XW = ws;                              // 10000*256
    float* z  = XW + (size_t)NN * HID;           // 10000*256
    float* zs = z  + (size_t)NN * HID;           // 10000*256
    float* a  = zs + (size_t)NN * HID;           // 10000
    float* b  = a + NN;                          // 10000
    float* c  = b + NN;                          // 512

    const dim3 blk(256);

    // XW = X @ W  (M=10000, K=512, N=256)
    dim3 g1((HID + BN - 1) / BN, (NN + BM - 1) / BM);
    gemm_f32<<<g1, blk, 0, stream>>>(X, W, XW, NN, IND, HID);

    // z = adj @ XW  (M=10000, K=10000, N=256)
    gemm_f32<<<g1, blk, 0, stream>>>(adj, XW, z, NN, NN, HID);

    // c = [u; v]
    k_uv<<<dim3(2), blk, 0, stream>>>(W2, W3, c);

    // per-node precompute
    k_node<<<dim3((NN * 64 + 255) / 256), blk, 0, stream>>>(z, c, W3, zs, a, b);

    // per-edge output
    k_edge<<<dim3((2 * NE * 64) / 256), blk, 0, stream>>>(e1, e2, z, zs, a, b, out);
}

// Round 2
// 560.053 us; speedup vs baseline: 2.0550x; 2.0550x over previous
//
#include <hip/hip_runtime.h>
#include <hip/hip_bf16.h>
#include <math.h>

#define NN   10000
#define IND  512
#define HID  256
#define NE   400000
#define KPAD 10048   // adj GEMM K padded to multiple of 64

typedef __attribute__((ext_vector_type(4))) float  f32x4;
typedef __attribute__((ext_vector_type(4))) int    i32x4;
typedef __attribute__((ext_vector_type(8))) short  bf16x8;

static __device__ inline ushort f2b(float f) {
    union { __hip_bfloat16 b; ushort u; } c;
    c.b = __float2bfloat16(f);
    return c.u;
}

static __device__ inline void gload_lds16(const void* g, void* l) {
    __builtin_amdgcn_global_load_lds(
        (const __attribute__((address_space(1))) unsigned int*)g,
        (__attribute__((address_space(3))) unsigned int*)l, 16, 0, 0);
}

// ---------------------------------------------------------------------------
// Transpose + convert: dst[c][r] = bf16(src[r][c]) for r<R else 0.
// dst is [C][Rpad] bf16. C % 64 == 0, Rpad % 64 == 0.
__global__ __launch_bounds__(256) void tr_cvt(
    const float* __restrict__ src, ushort* __restrict__ dst,
    int R, int C, int Rpad)
{
    __shared__ float t[64][65];
    const int r0 = blockIdx.x * 64, c0 = blockIdx.y * 64;
    const int tx = threadIdx.x & 63, ty = threadIdx.x >> 6;   // ty 0..3

    #pragma unroll
    for (int i = 0; i < 16; ++i) {
        const int rl = ty * 16 + i;
        const int r  = r0 + rl;
        float v = 0.f;
        if (r < R) v = src[(size_t)r * C + c0 + tx];
        t[rl][tx] = v;
    }
    __syncthreads();
    #pragma unroll
    for (int i = 0; i < 16; ++i) {
        const int cl = ty * 16 + i;
        dst[(size_t)(c0 + cl) * Rpad + r0 + tx] = f2b(t[tx][cl]);
    }
}

// ---------------------------------------------------------------------------
// C[M,N] (f32) = A[M,K] (f32, converted to bf16 on the fly) @ B, where B is
// given K-contiguous as BT[N][K_pad] bf16 (BT[n][k] = B[k][n]).
// BM=BN=64, BK=32, 256 threads = 4 waves (2x2), wave tile 32x32.
__global__ __launch_bounds__(256) void gemm_bf16(
    const float* __restrict__ A, const ushort* __restrict__ BT,
    float* __restrict__ C, int M, int K_real, int K_pad, int lda, int ldc)
{
    __shared__ ushort Alds[2048];   // [grp(4)][lane(64)][8 bf16] = 4 KB
    __shared__ ushort Blds[2048];

    const int tid  = threadIdx.x;
    const int lane = tid & 63;
    const int w    = tid >> 6;      // wave 0..3
    const int wm   = w >> 1, wn = w & 1;

    // --- bijective XCD-chunk swizzle of the flat block id
    const int nwg = gridDim.x * gridDim.y;
    const int lin = blockIdx.y * gridDim.x + blockIdx.x;
    const int q = nwg >> 3, r = nwg & 7;
    const int xc = lin & 7, o = lin >> 3;
    const int work = (xc < r ? xc * (q + 1) : r * (q + 1) + (xc - r) * q) + o;
    const int row0 = (work / gridDim.x) * 64;
    const int col0 = (work % gridDim.x) * 64;

    // --- A staging assignment: thread -> (row, kgroup)
    const int arow = tid >> 2;            // 0..63
    const int akg  = tid & 3;             // 0..3 (8 k each)
    const bool aok = (row0 + arow) < M;
    const float* aptr = A + (size_t)(row0 + arow) * lda + (akg << 3);
    ushort* awr = &Alds[(((arow >> 4) << 6) | (akg << 4) | (arow & 15)) << 3];

    // --- B staging: wave w stages fragment group w via global_load_lds
    const ushort* bptr = BT + (size_t)(col0 + (w << 4) + (lane & 15)) * K_pad
                            + ((lane >> 4) << 3);
    ushort* bwr = &Blds[w << 9];          // wave-uniform base (1 KB/group)

    f32x4 acc[2][2];
    #pragma unroll
    for (int i = 0; i < 2; ++i)
        #pragma unroll
        for (int j = 0; j < 2; ++j)
            acc[i][j] = (f32x4){0.f, 0.f, 0.f, 0.f};

    for (int k0 = 0; k0 < K_pad; k0 += 32) {
        // issue A global loads (regs) before the barrier
        f32x4 v0 = {0.f,0.f,0.f,0.f}, v1 = {0.f,0.f,0.f,0.f};
        const int gk = k0 + (akg << 3);
        if (aok && gk < K_real) {           // K_real % 8 == 0
            v0 = *reinterpret_cast<const f32x4*>(aptr + k0);
            v1 = *reinterpret_cast<const f32x4*>(aptr + k0 + 4);
        }
        __syncthreads();                    // prev-iter LDS reads done
        gload_lds16(bptr + k0, bwr);        // B: global -> LDS direct, 16 B/lane
        union { ushort u[8]; i32x4 v; } pk;
        pk.u[0] = f2b(v0.x); pk.u[1] = f2b(v0.y);
        pk.u[2] = f2b(v0.z); pk.u[3] = f2b(v0.w);
        pk.u[4] = f2b(v1.x); pk.u[5] = f2b(v1.y);
        pk.u[6] = f2b(v1.z); pk.u[7] = f2b(v1.w);
        *reinterpret_cast<i32x4*>(awr) = pk.v;
        __syncthreads();                    // waits vmcnt+lgkm (compiler)

        bf16x8 af[2], bf[2];
        #pragma unroll
        for (int mf = 0; mf < 2; ++mf)
            af[mf] = *reinterpret_cast<const bf16x8*>(
                &Alds[((((wm << 1) + mf) << 6) | lane) << 3]);
        #pragma unroll
        for (int nf = 0; nf < 2; ++nf)
            bf[nf] = *reinterpret_cast<const bf16x8*>(
                &Blds[((((wn << 1) + nf) << 6) | lane) << 3]);
        #pragma unroll
        for (int mf = 0; mf < 2; ++mf)
            #pragma unroll
            for (int nf = 0; nf < 2; ++nf)
                acc[mf][nf] = __builtin_amdgcn_mfma_f32_16x16x32_bf16(
                    af[mf], bf[nf], acc[mf][nf], 0, 0, 0);
    }

    // epilogue: C[row][col], col = lane&15, row = (lane>>4)*4 + reg
    #pragma unroll
    for (int mf = 0; mf < 2; ++mf) {
        const int rbase = row0 + wm * 32 + mf * 16 + ((lane >> 4) << 2);
        #pragma unroll
        for (int nf = 0; nf < 2; ++nf) {
            const int col = col0 + wn * 32 + nf * 16 + (lane & 15);
            #pragma unroll
            for (int rr = 0; rr < 4; ++rr) {
                const int row = rbase + rr;
                if (row < M) C[(size_t)row * ldc + col] = acc[mf][nf][rr];
            }
        }
    }
}

// ---------------------------------------------------------------------------
// c[j] = sum_m W2[j,m] * W3[m,0]
__global__ void k_uv(const float* __restrict__ W2, const float* __restrict__ W3,
                     float* __restrict__ c)
{
    const int j = blockIdx.x * blockDim.x + threadIdx.x;
    if (j >= 2 * HID) return;
    float s = 0.f;
    for (int m = 0; m < HID; ++m)
        s = fmaf(W2[(size_t)j * HID + m], W3[m], s);
    c[j] = s;
}

// ---------------------------------------------------------------------------
__global__ __launch_bounds__(256) void k_node(
    const float* __restrict__ z, const float* __restrict__ c,
    const float* __restrict__ W3, float* __restrict__ zs,
    float* __restrict__ av, float* __restrict__ bv)
{
    const int wave = (int)((blockIdx.x * blockDim.x + threadIdx.x) >> 6);
    const int lane = threadIdx.x & 63;
    if (wave >= NN) return;

    const f32x4 z4 = *reinterpret_cast<const f32x4*>(&z[(size_t)wave * HID + (lane << 2)]);
    const f32x4 w4 = *reinterpret_cast<const f32x4*>(&W3[HID + (lane << 2)]);
    const f32x4 u4 = *reinterpret_cast<const f32x4*>(&c[(lane << 2)]);
    const f32x4 v4 = *reinterpret_cast<const f32x4*>(&c[HID + (lane << 2)]);

    f32x4 zs4 = z4 * w4;
    *reinterpret_cast<f32x4*>(&zs[(size_t)wave * HID + (lane << 2)]) = zs4;

    const float r0 = fmaxf(z4.x, 0.f), r1 = fmaxf(z4.y, 0.f);
    const float r2 = fmaxf(z4.z, 0.f), r3 = fmaxf(z4.w, 0.f);
    float pa = r0 * u4.x + r1 * u4.y + r2 * u4.z + r3 * u4.w;
    float pb = r0 * v4.x + r1 * v4.y + r2 * v4.z + r3 * v4.w;

    #pragma unroll
    for (int off = 32; off; off >>= 1) {
        pa += __shfl_down(pa, off);
        pb += __shfl_down(pb, off);
    }
    if (lane == 0) { av[wave] = pa; bv[wave] = pb; }
}

// ---------------------------------------------------------------------------
__global__ __launch_bounds__(256) void k_edge(
    const int* __restrict__ e1, const int* __restrict__ e2,
    const float* __restrict__ z, const float* __restrict__ zs,
    const float* __restrict__ av, const float* __restrict__ bv,
    float* __restrict__ out)
{
    const long long gw = (((long long)blockIdx.x * blockDim.x) + threadIdx.x) >> 6;
    const int lane = threadIdx.x & 63;
    if (gw >= 2LL * NE) return;

    const int* ep = (gw < NE) ? &e1[2 * (int)gw] : &e2[2 * ((int)gw - NE)];
    const int i = ep[0];
    const int j = ep[1];

    const f32x4 zi = *reinterpret_cast<const f32x4*>(&zs[(size_t)i * HID + (lane << 2)]);
    const f32x4 zj = *reinterpret_cast<const f32x4*>(&z[(size_t)j * HID + (lane << 2)]);
    float p = zi.x * zj.x + zi.y * zj.y + zi.z * zj.z + zi.w * zj.w;

    #pragma unroll
    for (int off = 32; off; off >>= 1)
        p += __shfl_down(p, off);

    if (lane == 0) {
        const float logit = av[i] + bv[j] + p;
        out[gw] = 1.f / (1.f + expf(-logit));
    }
}

// ---------------------------------------------------------------------------
extern "C" void kernel_launch(void* const* d_in, const int* in_sizes, int n_in,
                              void* d_out, int out_size, void* d_ws, size_t ws_size,
                              hipStream_t stream)
{
    const float* X   = (const float*)d_in[0];
    const float* adj = (const float*)d_in[1];
    const int*   e1  = (const int*)d_in[2];
    const int*   e2  = (const int*)d_in[3];
    const float* W   = (const float*)d_in[4];
    const float* W2  = (const float*)d_in[5];
    const float* W3  = (const float*)d_in[6];
    float* out = (float*)d_out;

    float* ws = (float*)d_ws;
    float*  XW   = ws;                                   // 10000*256
    float*  z    = XW + (size_t)NN * HID;                // 10000*256
    float*  zs   = z  + (size_t)NN * HID;                // 10000*256
    float*  a    = zs + (size_t)NN * HID;                // 10000
    float*  b    = a + NN;                               // 10000
    float*  c    = b + NN;                               // 512
    ushort* WTb  = (ushort*)(c + 512);                   // 256 x 512
    ushort* XWbT = WTb + (size_t)HID * IND;              // 256 x 10048

    const dim3 blk(256);

    // WTb[c][k] = bf16(W[k][c]),  [256][512]
    tr_cvt<<<dim3(IND / 64, HID / 64), blk, 0, stream>>>(W, WTb, IND, HID, IND);

    // XW = X @ W   (MFMA, K=512)
    gemm_bf16<<<dim3(HID / 64, 157), blk, 0, stream>>>(X, WTb, XW, NN, IND, IND, IND, HID);

    // XWbT[c][k] = bf16(XW[k][c]), [256][10048], zero-padded k>=10000
    tr_cvt<<<dim3(KPAD / 64, HID / 64), blk, 0, stream>>>(XW, XWbT, NN, HID, KPAD);

    // z = adj @ XW  (MFMA, K=10000 padded to 10048)
    gemm_bf16<<<dim3(HID / 64, 157), blk, 0, stream>>>(adj, XWbT, z, NN, NN, KPAD, NN, HID);

    // c = [u; v]
    k_uv<<<dim3(2), blk, 0, stream>>>(W2, W3, c);

    // per-node precompute
    k_node<<<dim3((NN * 64 + 255) / 256), blk, 0, stream>>>(z, c, W3, zs, a, b);

    // per-edge output
    k_edge<<<dim3((2 * NE * 64) / 256), blk, 0, stream>>>(e1, e2, z, zs, a, b, out);
}

// Round 3
// 404.042 us; speedup vs baseline: 2.8485x; 1.3861x over previous
//
#include <hip/hip_runtime.h>
#include <hip/hip_bf16.h>
#include <math.h>

#define NN   10000
#define IND  512
#define HID  256
#define NE   400000
#define KPAD 10240   // adj GEMM K padded (multiple of 64*SK)
#define SK   4       // split-K factor for adj GEMM
#define KCH  2560    // K chunk per split (KPAD/SK)

typedef __attribute__((ext_vector_type(4))) float  f32x4;
typedef __attribute__((ext_vector_type(4))) int    i32x4;
typedef __attribute__((ext_vector_type(2))) uint   u32x2;
typedef __attribute__((ext_vector_type(8))) short  bf16x8;

static __device__ inline ushort f2b(float f) {
    union { __hip_bfloat16 b; ushort u; } c;
    c.b = __float2bfloat16(f);
    return c.u;
}
static __device__ inline float b2f(ushort u) {
    union { uint t; float f; } c;
    c.t = (uint)u << 16;
    return c.f;
}
static __device__ inline void gload_lds16(const void* g, void* l) {
    __builtin_amdgcn_global_load_lds(
        (const __attribute__((address_space(1))) unsigned int*)g,
        (__attribute__((address_space(3))) unsigned int*)l, 16, 0, 0);
}

// ---------------------------------------------------------------------------
// Transpose + convert: dst[c][r] = bf16(src[r][c]) for r<R else 0.
__global__ __launch_bounds__(256) void tr_cvt(
    const float* __restrict__ src, ushort* __restrict__ dst,
    int R, int C, int Rpad)
{
    __shared__ float t[64][65];
    const int r0 = blockIdx.x * 64, c0 = blockIdx.y * 64;
    const int tx = threadIdx.x & 63, ty = threadIdx.x >> 6;

    #pragma unroll
    for (int i = 0; i < 16; ++i) {
        const int rl = ty * 16 + i;
        const int r  = r0 + rl;
        float v = 0.f;
        if (r < R) v = src[(size_t)r * C + c0 + tx];
        t[rl][tx] = v;
    }
    __syncthreads();
    #pragma unroll
    for (int i = 0; i < 16; ++i) {
        const int cl = ty * 16 + i;
        dst[(size_t)(c0 + cl) * Rpad + r0 + tx] = f2b(t[tx][cl]);
    }
}

// ---------------------------------------------------------------------------
// Split-K GEMM: Cpart[sk][M,N] = A[M, kbeg:kbeg+k_chunk] @ B(chunk), A f32
// converted on the fly, B given K-contiguous bf16 as BT[N][ld_bt].
// BM=BN=64, BK=32, 4 waves (2x2), wave tile 32x32.
__global__ __launch_bounds__(256) void gemm_bf16(
    const float* __restrict__ A, const ushort* __restrict__ BT,
    float* __restrict__ C, int M, int K_real, int ld_bt, int lda, int ldc,
    int k_chunk, size_t c_stride)
{
    __shared__ ushort Alds[2048];
    __shared__ ushort Blds[2048];

    const int tid  = threadIdx.x;
    const int lane = tid & 63;
    const int w    = tid >> 6;
    const int wm   = w >> 1, wn = w & 1;

    // bijective XCD-chunk swizzle over the whole 3D grid (col fastest)
    const int gx = gridDim.x, gy = gridDim.y;
    const int nwg = gx * gy * gridDim.z;
    const int lin = (blockIdx.z * gy + blockIdx.y) * gx + blockIdx.x;
    const int q = nwg >> 3, r = nwg & 7;
    const int xc = lin & 7, o = lin >> 3;
    const int work = (xc < r ? xc * (q + 1) : r * (q + 1) + (xc - r) * q) + o;
    const int col0 = (work % gx) * 64;
    const int row0 = ((work / gx) % gy) * 64;
    const int sk   = work / (gx * gy);
    const int kbeg = sk * k_chunk;
    C += (size_t)sk * c_stride;

    // A staging: thread -> (row, kgroup of 8)
    const int arow = tid >> 2;
    const int akg  = tid & 3;
    const bool aok = (row0 + arow) < M;
    const float* aptr = A + (size_t)(row0 + arow) * lda + kbeg + (akg << 3);
    ushort* awr = &Alds[(((arow >> 4) << 6) | (akg << 4) | (arow & 15)) << 3];

    // B staging: wave w stages fragment group w via global_load_lds
    const ushort* bptr = BT + (size_t)(col0 + (w << 4) + (lane & 15)) * ld_bt
                            + kbeg + ((lane >> 4) << 3);
    ushort* bwr = &Blds[w << 9];

    f32x4 acc[2][2];
    #pragma unroll
    for (int i = 0; i < 2; ++i)
        #pragma unroll
        for (int j = 0; j < 2; ++j)
            acc[i][j] = (f32x4){0.f, 0.f, 0.f, 0.f};

    // prologue A load (k0 = 0)
    f32x4 v0 = {0.f,0.f,0.f,0.f}, v1 = {0.f,0.f,0.f,0.f};
    if (aok && (kbeg + (akg << 3)) < K_real) {
        v0 = *reinterpret_cast<const f32x4*>(aptr);
        v1 = *reinterpret_cast<const f32x4*>(aptr + 4);
    }

    for (int k0 = 0; k0 < k_chunk; k0 += 32) {
        __syncthreads();                    // prev-iter LDS reads done
        gload_lds16(bptr + k0, bwr);        // B: global -> LDS direct
        union { ushort u[8]; i32x4 v; } pk;
        pk.u[0] = f2b(v0.x); pk.u[1] = f2b(v0.y);
        pk.u[2] = f2b(v0.z); pk.u[3] = f2b(v0.w);
        pk.u[4] = f2b(v1.x); pk.u[5] = f2b(v1.y);
        pk.u[6] = f2b(v1.z); pk.u[7] = f2b(v1.w);
        *reinterpret_cast<i32x4*>(awr) = pk.v;
        __syncthreads();                    // drains B gload + A writes

        // prefetch next-iter A regs (in flight across MFMA section)
        const int kn = k0 + 32;
        v0 = (f32x4){0.f,0.f,0.f,0.f};
        v1 = (f32x4){0.f,0.f,0.f,0.f};
        if (kn < k_chunk && aok && (kbeg + kn + (akg << 3)) < K_real) {
            v0 = *reinterpret_cast<const f32x4*>(aptr + kn);
            v1 = *reinterpret_cast<const f32x4*>(aptr + kn + 4);
        }

        bf16x8 af[2], bfr[2];
        #pragma unroll
        for (int mf = 0; mf < 2; ++mf)
            af[mf] = *reinterpret_cast<const bf16x8*>(
                &Alds[((((wm << 1) + mf) << 6) | lane) << 3]);
        #pragma unroll
        for (int nf = 0; nf < 2; ++nf)
            bfr[nf] = *reinterpret_cast<const bf16x8*>(
                &Blds[((((wn << 1) + nf) << 6) | lane) << 3]);
        #pragma unroll
        for (int mf = 0; mf < 2; ++mf)
            #pragma unroll
            for (int nf = 0; nf < 2; ++nf)
                acc[mf][nf] = __builtin_amdgcn_mfma_f32_16x16x32_bf16(
                    af[mf], bfr[nf], acc[mf][nf], 0, 0, 0);
    }

    #pragma unroll
    for (int mf = 0; mf < 2; ++mf) {
        const int rbase = row0 + wm * 32 + mf * 16 + ((lane >> 4) << 2);
        #pragma unroll
        for (int nf = 0; nf < 2; ++nf) {
            const int col = col0 + wn * 32 + nf * 16 + (lane & 15);
            #pragma unroll
            for (int rr = 0; rr < 4; ++rr) {
                const int row = rbase + rr;
                if (row < M) C[(size_t)row * ldc + col] = acc[mf][nf][rr];
            }
        }
    }
}

// ---------------------------------------------------------------------------
__global__ void k_uv(const float* __restrict__ W2, const float* __restrict__ W3,
                     float* __restrict__ c)
{
    const int j = blockIdx.x * blockDim.x + threadIdx.x;
    if (j >= 2 * HID) return;
    float s = 0.f;
    for (int m = 0; m < HID; ++m)
        s = fmaf(W2[(size_t)j * HID + m], W3[m], s);
    c[j] = s;
}

// ---------------------------------------------------------------------------
// Fused split-K reduce + per-node precompute:
//   z = sum_sk Cpart[sk];  zb = bf16(z);  zsb = bf16(z*w3b);
//   a = relu(z)·u;  b = relu(z)·v
__global__ __launch_bounds__(256) void k_node(
    const float* __restrict__ Cpart, const float* __restrict__ c,
    const float* __restrict__ W3, ushort* __restrict__ zb,
    ushort* __restrict__ zsb, float* __restrict__ av, float* __restrict__ bv)
{
    const int node = (int)((blockIdx.x * blockDim.x + threadIdx.x) >> 6);
    const int lane = threadIdx.x & 63;
    if (node >= NN) return;

    const float* p0 = Cpart + (size_t)node * HID + (lane << 2);
    f32x4 s = *reinterpret_cast<const f32x4*>(p0);
    s += *reinterpret_cast<const f32x4*>(p0 + (size_t)NN * HID);
    s += *reinterpret_cast<const f32x4*>(p0 + 2 * (size_t)NN * HID);
    s += *reinterpret_cast<const f32x4*>(p0 + 3 * (size_t)NN * HID);

    const f32x4 w4 = *reinterpret_cast<const f32x4*>(&W3[HID + (lane << 2)]);
    const f32x4 u4 = *reinterpret_cast<const f32x4*>(&c[(lane << 2)]);
    const f32x4 v4 = *reinterpret_cast<const f32x4*>(&c[HID + (lane << 2)]);
    const f32x4 zs4 = s * w4;

    union { ushort u[4]; u32x2 v; } pz, ps;
    pz.u[0] = f2b(s.x);   pz.u[1] = f2b(s.y);
    pz.u[2] = f2b(s.z);   pz.u[3] = f2b(s.w);
    ps.u[0] = f2b(zs4.x); ps.u[1] = f2b(zs4.y);
    ps.u[2] = f2b(zs4.z); ps.u[3] = f2b(zs4.w);
    *reinterpret_cast<u32x2*>(&zb [(size_t)node * HID + (lane << 2)]) = pz.v;
    *reinterpret_cast<u32x2*>(&zsb[(size_t)node * HID + (lane << 2)]) = ps.v;

    const float r0 = fmaxf(s.x, 0.f), r1 = fmaxf(s.y, 0.f);
    const float r2 = fmaxf(s.z, 0.f), r3 = fmaxf(s.w, 0.f);
    float pa = r0 * u4.x + r1 * u4.y + r2 * u4.z + r3 * u4.w;
    float pb = r0 * v4.x + r1 * v4.y + r2 * v4.z + r3 * v4.w;

    #pragma unroll
    for (int off = 32; off; off >>= 1) {
        pa += __shfl_down(pa, off);
        pb += __shfl_down(pb, off);
    }
    if (lane == 0) { av[node] = pa; bv[node] = pb; }
}

// ---------------------------------------------------------------------------
// 2 edges per wave (32 lanes each): out = sigmoid(a[i]+b[j]+dot(zs[i],z[j]))
__global__ __launch_bounds__(256) void k_edge(
    const int* __restrict__ e1, const int* __restrict__ e2,
    const ushort* __restrict__ zb, const ushort* __restrict__ zsb,
    const float* __restrict__ av, const float* __restrict__ bv,
    float* __restrict__ out)
{
    const long long wid = (((long long)blockIdx.x * blockDim.x) + threadIdx.x) >> 6;
    const int lane = threadIdx.x & 63;
    const int half = lane >> 5;
    const int l32  = lane & 31;
    const long long e = 2LL * wid + half;
    if (e >= 2LL * NE) return;

    const int* ep = (e < NE) ? &e1[2 * (int)e] : &e2[2 * ((int)e - NE)];
    const int i = ep[0];
    const int j = ep[1];

    const bf16x8 zi = *reinterpret_cast<const bf16x8*>(&zsb[(size_t)i * HID + (l32 << 3)]);
    const bf16x8 zj = *reinterpret_cast<const bf16x8*>(&zb [(size_t)j * HID + (l32 << 3)]);
    float p = 0.f;
    #pragma unroll
    for (int t = 0; t < 8; ++t)
        p = fmaf(b2f((ushort)zi[t]), b2f((ushort)zj[t]), p);

    #pragma unroll
    for (int m = 16; m; m >>= 1)
        p += __shfl_xor(p, m);

    if (l32 == 0) {
        const float logit = av[i] + bv[j] + p;
        out[e] = 1.f / (1.f + expf(-logit));
    }
}

// ---------------------------------------------------------------------------
extern "C" void kernel_launch(void* const* d_in, const int* in_sizes, int n_in,
                              void* d_out, int out_size, void* d_ws, size_t ws_size,
                              hipStream_t stream)
{
    const float* X   = (const float*)d_in[0];
    const float* adj = (const float*)d_in[1];
    const int*   e1  = (const int*)d_in[2];
    const int*   e2  = (const int*)d_in[3];
    const float* W   = (const float*)d_in[4];
    const float* W2  = (const float*)d_in[5];
    const float* W3  = (const float*)d_in[6];
    float* out = (float*)d_out;

    float* ws = (float*)d_ws;
    float*  XW    = ws;                                  // NN*HID
    float*  a     = XW + (size_t)NN * HID;               // NN
    float*  b     = a + NN;                              // NN
    float*  c     = b + NN;                              // 512
    float*  Cpart = c + 512;                             // SK*NN*HID
    ushort* WTb   = (ushort*)(Cpart + (size_t)SK * NN * HID);  // HID*IND
    ushort* XWbT  = WTb  + (size_t)HID * IND;            // HID*KPAD
    ushort* zb    = XWbT + (size_t)HID * KPAD;           // NN*HID
    ushort* zsb   = zb   + (size_t)NN * HID;             // NN*HID

    const dim3 blk(256);

    // WTb[c][k] = bf16(W[k][c])
    tr_cvt<<<dim3(IND / 64, HID / 64), blk, 0, stream>>>(W, WTb, IND, HID, IND);

    // XW = X @ W  (single chunk)
    gemm_bf16<<<dim3(HID / 64, 157, 1), blk, 0, stream>>>(
        X, WTb, XW, NN, IND, IND, IND, HID, IND, 0);

    // XWbT[c][k] = bf16(XW[k][c]), zero-padded to KPAD
    tr_cvt<<<dim3(KPAD / 64, HID / 64), blk, 0, stream>>>(XW, XWbT, NN, HID, KPAD);

    // Cpart[sk] = adj @ XW chunk  (split-K = 4)
    gemm_bf16<<<dim3(HID / 64, 157, SK), blk, 0, stream>>>(
        adj, XWbT, Cpart, NN, NN, KPAD, NN, HID, KCH, (size_t)NN * HID);

    // c = [u; v]
    k_uv<<<dim3(2), blk, 0, stream>>>(W2, W3, c);

    // reduce partials + per-node tables
    k_node<<<dim3((NN * 64) / 256 + 1), blk, 0, stream>>>(Cpart, c, W3, zb, zsb, a, b);

    // per-edge output (2 edges / wave)
    k_edge<<<dim3((2 * NE / 2 * 64) / 256), blk, 0, stream>>>(e1, e2, zb, zsb, a, b, out);
}

// Round 4
// 387.427 us; speedup vs baseline: 2.9706x; 1.0429x over previous
//
#include <hip/hip_runtime.h>
#include <hip/hip_bf16.h>
#include <math.h>

#define NN   10000
#define IND  512
#define HID  256
#define NE   400000
#define KPAD 10240   // adj GEMM K padded
#define SKA  4       // split-K adj GEMM   (KCHA = 2560)
#define KCHA 2560
#define SKX  4       // split-K X@W GEMM   (KCHX = 128)
#define KCHX 128

typedef __attribute__((ext_vector_type(4))) float  f32x4;
typedef __attribute__((ext_vector_type(4))) int    i32x4;
typedef __attribute__((ext_vector_type(2))) uint   u32x2;
typedef __attribute__((ext_vector_type(8))) short  bf16x8;

static __device__ inline ushort f2b(float f) {
    union { __hip_bfloat16 b; ushort u; } c;
    c.b = __float2bfloat16(f);
    return c.u;
}
static __device__ inline float b2f(ushort u) {
    union { uint t; float f; } c;
    c.t = (uint)u << 16;
    return c.f;
}
static __device__ inline void gload_lds16(const void* g, void* l) {
    __builtin_amdgcn_global_load_lds(
        (const __attribute__((address_space(1))) unsigned int*)g,
        (__attribute__((address_space(3))) unsigned int*)l, 16, 0, 0);
}

// ---------------------------------------------------------------------------
// Reduce (over nparts) + transpose + convert: dst[c][r] = bf16(sum_p src[p][r][c])
// for r < R else 0. dst is [C][Rpad] bf16.
__global__ __launch_bounds__(256) void tr_cvt_red(
    const float* __restrict__ src, ushort* __restrict__ dst,
    int R, int C, int Rpad, int nparts, size_t pstride)
{
    __shared__ float t[64][65];
    const int r0 = blockIdx.x * 64, c0 = blockIdx.y * 64;
    const int tx = threadIdx.x & 63, ty = threadIdx.x >> 6;

    #pragma unroll
    for (int i = 0; i < 16; ++i) {
        const int rl = ty * 16 + i;
        const int r  = r0 + rl;
        float v = 0.f;
        if (r < R) {
            const float* p = src + (size_t)r * C + c0 + tx;
            for (int q = 0; q < nparts; ++q) v += p[q * pstride];
        }
        t[rl][tx] = v;
    }
    __syncthreads();
    #pragma unroll
    for (int i = 0; i < 16; ++i) {
        const int cl = ty * 16 + i;
        dst[(size_t)(c0 + cl) * Rpad + r0 + tx] = f2b(t[tx][cl]);
    }
}

// ---------------------------------------------------------------------------
// C[M,256] split-K GEMM, full-width N=256 (single col tile -> A fetched once).
// A f32 (cvt to bf16 on the fly), B K-contiguous bf16 BT[256][ld_bt].
// Block: 64 rows x 256 cols, 4 waves, wave tile 64x64, BK=32.
// LDS layout slot-linear: slot s = (grp<<4)|elem16, 16B per slot; all LDS ops
// conflict-free.
__global__ __launch_bounds__(256, 4) void gemm_n256(
    const float* __restrict__ A, const ushort* __restrict__ BT,
    float* __restrict__ C, int M, int K_real, int ld_bt, int lda,
    int k_chunk, size_t c_stride)
{
    __shared__ ushort Alds[2048];   //  4 KB: 4 rowgrp x 4 kgrp x 16 row x 8
    __shared__ ushort Blds[8192];   // 16 KB: 16 colgrp x 4 kgrp x 16 col x 8

    const int tid  = threadIdx.x;
    const int lane = tid & 63;
    const int w    = tid >> 6;      // wave 0..3 = col quadrant

    // bijective XCD-chunk swizzle; work ordered row-fastest, sk-major
    const int nwg = gridDim.x * gridDim.y;
    const int lin = blockIdx.y * gridDim.x + blockIdx.x;
    const int q = nwg >> 3, r = nwg & 7;
    const int xc = lin & 7, o = lin >> 3;
    const int work = (xc < r ? xc * (q + 1) : r * (q + 1) + (xc - r) * q) + o;
    const int row0 = (work % gridDim.x) * 64;
    const int sk   = work / gridDim.x;
    const int kbeg = sk * k_chunk;
    C += (size_t)sk * c_stride;

    // A staging: thread t -> slot t: rowgrp=t>>6, kgrp=(t>>4)&3, row16=t&15
    const int arow = ((tid >> 6) << 4) | (tid & 15);
    const int akg  = (tid >> 4) & 3;
    const bool aok = (row0 + arow) < M;
    const float* aptr = A + (size_t)(row0 + arow) * lda + kbeg + (akg << 3);
    ushort* awr = &Alds[tid << 3];

    // B staging: wave w stages colgrps 4w..4w+3; lane l -> col (l&15), kgrp l>>4
    const ushort* bsrc0 = BT + (size_t)((w << 6) + (lane & 15)) * ld_bt
                             + kbeg + ((lane >> 4) << 3);

    f32x4 acc[4][4];
    #pragma unroll
    for (int i = 0; i < 4; ++i)
        #pragma unroll
        for (int j = 0; j < 4; ++j)
            acc[i][j] = (f32x4){0.f, 0.f, 0.f, 0.f};

    // prologue A load
    f32x4 v0 = {0.f,0.f,0.f,0.f}, v1 = {0.f,0.f,0.f,0.f};
    if (aok && (kbeg + (akg << 3)) < K_real) {
        v0 = *reinterpret_cast<const f32x4*>(aptr);
        v1 = *reinterpret_cast<const f32x4*>(aptr + 4);
    }

    for (int k0 = 0; k0 < k_chunk; k0 += 32) {
        __syncthreads();                       // prev-iter LDS reads done
        #pragma unroll
        for (int g = 0; g < 4; ++g)            // B: global -> LDS direct
            gload_lds16(bsrc0 + (size_t)(g << 4) * ld_bt + k0,
                        &Blds[(((w << 2) + g) << 9)]);
        union { ushort u[8]; i32x4 v; } pk;
        pk.u[0] = f2b(v0.x); pk.u[1] = f2b(v0.y);
        pk.u[2] = f2b(v0.z); pk.u[3] = f2b(v0.w);
        pk.u[4] = f2b(v1.x); pk.u[5] = f2b(v1.y);
        pk.u[6] = f2b(v1.z); pk.u[7] = f2b(v1.w);
        *reinterpret_cast<i32x4*>(awr) = pk.v;
        __syncthreads();                       // drains B gloads + A writes

        // prefetch next-iter A into regs (in flight across MFMA section)
        const int kn = k0 + 32;
        v0 = (f32x4){0.f,0.f,0.f,0.f};
        v1 = (f32x4){0.f,0.f,0.f,0.f};
        if (kn < k_chunk && aok && (kbeg + kn + (akg << 3)) < K_real) {
            v0 = *reinterpret_cast<const f32x4*>(aptr + kn);
            v1 = *reinterpret_cast<const f32x4*>(aptr + kn + 4);
        }

        bf16x8 bfr[4];
        #pragma unroll
        for (int nf = 0; nf < 4; ++nf)
            bfr[nf] = *reinterpret_cast<const bf16x8*>(
                &Blds[(((((w << 2) + nf) << 6) | lane) << 3)]);
        #pragma unroll
        for (int mf = 0; mf < 4; ++mf) {
            const bf16x8 af = *reinterpret_cast<const bf16x8*>(
                &Alds[(((mf << 6) | lane) << 3)]);
            #pragma unroll
            for (int nf = 0; nf < 4; ++nf)
                acc[mf][nf] = __builtin_amdgcn_mfma_f32_16x16x32_bf16(
                    af, bfr[nf], acc[mf][nf], 0, 0, 0);
        }
    }

    // epilogue: col = lane&15, row = (lane>>4)*4 + rr
    #pragma unroll
    for (int mf = 0; mf < 4; ++mf) {
        const int rbase = row0 + mf * 16 + ((lane >> 4) << 2);
        #pragma unroll
        for (int nf = 0; nf < 4; ++nf) {
            const int col = (w << 6) + nf * 16 + (lane & 15);
            #pragma unroll
            for (int rr = 0; rr < 4; ++rr) {
                const int row = rbase + rr;
                if (row < M) C[(size_t)row * HID + col] = acc[mf][nf][rr];
            }
        }
    }
}

// ---------------------------------------------------------------------------
__global__ void k_uv(const float* __restrict__ W2, const float* __restrict__ W3,
                     float* __restrict__ c)
{
    const int j = blockIdx.x * blockDim.x + threadIdx.x;
    if (j >= 2 * HID) return;
    float s = 0.f;
    for (int m = 0; m < HID; ++m)
        s = fmaf(W2[(size_t)j * HID + m], W3[m], s);
    c[j] = s;
}

// ---------------------------------------------------------------------------
// Fused split-K reduce + per-node tables (bf16) + a,b scalars
__global__ __launch_bounds__(256) void k_node(
    const float* __restrict__ Cpart, const float* __restrict__ c,
    const float* __restrict__ W3, ushort* __restrict__ zb,
    ushort* __restrict__ zsb, float* __restrict__ av, float* __restrict__ bv)
{
    const int node = (int)((blockIdx.x * blockDim.x + threadIdx.x) >> 6);
    const int lane = threadIdx.x & 63;
    if (node >= NN) return;

    const float* p0 = Cpart + (size_t)node * HID + (lane << 2);
    f32x4 s = *reinterpret_cast<const f32x4*>(p0);
    #pragma unroll
    for (int p = 1; p < SKA; ++p)
        s += *reinterpret_cast<const f32x4*>(p0 + (size_t)p * NN * HID);

    const f32x4 w4 = *reinterpret_cast<const f32x4*>(&W3[HID + (lane << 2)]);
    const f32x4 u4 = *reinterpret_cast<const f32x4*>(&c[(lane << 2)]);
    const f32x4 v4 = *reinterpret_cast<const f32x4*>(&c[HID + (lane << 2)]);
    const f32x4 zs4 = s * w4;

    union { ushort u[4]; u32x2 v; } pz, ps;
    pz.u[0] = f2b(s.x);   pz.u[1] = f2b(s.y);
    pz.u[2] = f2b(s.z);   pz.u[3] = f2b(s.w);
    ps.u[0] = f2b(zs4.x); ps.u[1] = f2b(zs4.y);
    ps.u[2] = f2b(zs4.z); ps.u[3] = f2b(zs4.w);
    *reinterpret_cast<u32x2*>(&zb [(size_t)node * HID + (lane << 2)]) = pz.v;
    *reinterpret_cast<u32x2*>(&zsb[(size_t)node * HID + (lane << 2)]) = ps.v;

    const float r0 = fmaxf(s.x, 0.f), r1 = fmaxf(s.y, 0.f);
    const float r2 = fmaxf(s.z, 0.f), r3 = fmaxf(s.w, 0.f);
    float pa = r0 * u4.x + r1 * u4.y + r2 * u4.z + r3 * u4.w;
    float pb = r0 * v4.x + r1 * v4.y + r2 * v4.z + r3 * v4.w;

    #pragma unroll
    for (int off = 32; off; off >>= 1) {
        pa += __shfl_down(pa, off);
        pb += __shfl_down(pb, off);
    }
    if (lane == 0) { av[node] = pa; bv[node] = pb; }
}

// ---------------------------------------------------------------------------
// 2 edges per wave (32 lanes each): out = sigmoid(a[i]+b[j]+dot(zs[i],z[j]))
__global__ __launch_bounds__(256) void k_edge(
    const int* __restrict__ e1, const int* __restrict__ e2,
    const ushort* __restrict__ zb, const ushort* __restrict__ zsb,
    const float* __restrict__ av, const float* __restrict__ bv,
    float* __restrict__ out)
{
    const long long wid = (((long long)blockIdx.x * blockDim.x) + threadIdx.x) >> 6;
    const int lane = threadIdx.x & 63;
    const int half = lane >> 5;
    const int l32  = lane & 31;
    const long long e = 2LL * wid + half;
    if (e >= 2LL * NE) return;

    const int* ep = (e < NE) ? &e1[2 * (int)e] : &e2[2 * ((int)e - NE)];
    const int i = ep[0];
    const int j = ep[1];

    const bf16x8 zi = *reinterpret_cast<const bf16x8*>(&zsb[(size_t)i * HID + (l32 << 3)]);
    const bf16x8 zj = *reinterpret_cast<const bf16x8*>(&zb [(size_t)j * HID + (l32 << 3)]);
    float p = 0.f;
    #pragma unroll
    for (int t = 0; t < 8; ++t)
        p = fmaf(b2f((ushort)zi[t]), b2f((ushort)zj[t]), p);

    #pragma unroll
    for (int m = 16; m; m >>= 1)
        p += __shfl_xor(p, m);

    if (l32 == 0) {
        const float logit = av[i] + bv[j] + p;
        out[e] = 1.f / (1.f + expf(-logit));
    }
}

// ---------------------------------------------------------------------------
extern "C" void kernel_launch(void* const* d_in, const int* in_sizes, int n_in,
                              void* d_out, int out_size, void* d_ws, size_t ws_size,
                              hipStream_t stream)
{
    const float* X   = (const float*)d_in[0];
    const float* adj = (const float*)d_in[1];
    const int*   e1  = (const int*)d_in[2];
    const int*   e2  = (const int*)d_in[3];
    const float* W   = (const float*)d_in[4];
    const float* W2  = (const float*)d_in[5];
    const float* W3  = (const float*)d_in[6];
    float* out = (float*)d_out;

    float*  ws   = (float*)d_ws;
    float*  a    = ws;                                   // NN
    float*  b    = a + NN;                               // NN
    float*  c    = b + NN;                               // 512
    ushort* WTb  = (ushort*)(c + 512);                   // HID*IND
    ushort* XWbT = WTb  + (size_t)HID * IND;             // HID*KPAD
    ushort* zb   = XWbT + (size_t)HID * KPAD;            // NN*HID
    ushort* zsb  = zb   + (size_t)NN * HID;              // NN*HID
    float*  big  = (float*)(zsb + (size_t)NN * HID);     // SK*NN*HID (XWpart, then Cpart)

    const dim3 blk(256);

    // WTb[c][k] = bf16(W[k][c])
    tr_cvt_red<<<dim3(IND / 64, HID / 64), blk, 0, stream>>>(W, WTb, IND, HID, IND, 1, 0);

    // XWpart = X @ W  (split-K = 4)
    gemm_n256<<<dim3(157, SKX), blk, 0, stream>>>(
        X, WTb, big, NN, IND, IND, IND, KCHX, (size_t)NN * HID);

    // XWbT[c][k] = bf16(sum_p XWpart[p][k][c]), zero-padded to KPAD
    tr_cvt_red<<<dim3(KPAD / 64, HID / 64), blk, 0, stream>>>(
        big, XWbT, NN, HID, KPAD, SKX, (size_t)NN * HID);

    // Cpart = adj @ XW  (split-K = 4, single col tile: adj fetched once)
    gemm_n256<<<dim3(157, SKA), blk, 0, stream>>>(
        adj, XWbT, big, NN, NN, KPAD, NN, KCHA, (size_t)NN * HID);

    // c = [u; v]
    k_uv<<<dim3(2), blk, 0, stream>>>(W2, W3, c);

    // reduce partials + per-node tables
    k_node<<<dim3((NN * 64) / 256), blk, 0, stream>>>(big, c, W3, zb, zsb, a, b);

    // per-edge output (2 edges / wave)
    k_edge<<<dim3((NE * 64) / 256), blk, 0, stream>>>(e1, e2, zb, zsb, a, b, out);
}